// Round 1
// baseline (5937.225 us; speedup 1.0000x reference)
//
#include <hip/hip_runtime.h>
#include <math.h>

namespace {

constexpr int B = 16, C = 128, H = 64, W = 64;
constexpr int NO = 4 * C;        // 512 gate outputs
constexpr int KV = 3 * C;        // 384 = [x | h_shift | h]
constexpr int VPAD = KV + 4;     // 388: LDS row stride (bank decorrelation)
constexpr int WSKEW = W + H - 1; // 127 scan steps

// Pack W into [512][384] rows: [w_is | w_ss(:,:,0) | w_ss(:,:,1)], bias = b_is + b_ss.
__global__ void pack_weights(const float* __restrict__ w_is,
                             const float* __restrict__ b_is,
                             const float* __restrict__ w_ss,
                             const float* __restrict__ b_ss,
                             float* __restrict__ Wcat,
                             float* __restrict__ biasW) {
    int o = blockIdx.x;
    int c = threadIdx.x;
    Wcat[o * KV + c]          = w_is[o * C + c];
    Wcat[o * KV + C + c]      = w_ss[(o * C + c) * 2 + 0];
    Wcat[o * KV + 2 * C + c]  = w_ss[(o * C + c) * 2 + 1];
    if (c == 0) biasW[o] = b_is[o] + b_ss[o];
}

// x [B][C][H][W] -> xT [B][H][W][C]  (coalesced per-position channel vectors)
__global__ void transpose_x(const float* __restrict__ x, float* __restrict__ xT) {
    __shared__ float tile[C][W + 1];
    int b = blockIdx.x >> 6, row = blockIdx.x & 63;
    int tid = threadIdx.x;
#pragma unroll
    for (int i = 0; i < (C * W) / 256; ++i) {
        int idx = i * 256 + tid;
        int c = idx >> 6, w = idx & 63;
        tile[c][w] = x[((b * C + c) * H + row) * W + w];
    }
    __syncthreads();
#pragma unroll
    for (int i = 0; i < (C * W) / 256; ++i) {
        int idx = i * 256 + tid;
        int w = idx >> 7, c = idx & 127;
        xT[((b * H + row) * W + w) * C + c] = tile[c][w];
    }
}

// One diagonal step t. Grid: 256 blocks = 64 pos-groups (16 rows of one batch) x 4 channel-groups.
// Block: 256 threads = 8 pos-pairs x 32 channels; each thread computes the 4 gates of one
// channel for 2 positions, then updates c/h locally.
__global__ __launch_bounds__(256) void lstm_step(
        const float* __restrict__ xT, const float* __restrict__ Wcat,
        const float* __restrict__ biasW, const float* __restrict__ h_prev,
        float* __restrict__ h_cur, float* __restrict__ c_buf,
        float* __restrict__ hist, int t) {
    __shared__ float v[16][VPAD];

    int bid = blockIdx.x;
    int pg = bid >> 2, cg = bid & 3;
    int b = pg >> 2, rg = pg & 3;
    int r0 = rg * 16;
    int tid = threadIdx.x;

    // ---- stage v = [x(skewed) | h_shift | h] for 16 positions ----
    {
        int p = tid >> 4, l = tid & 15;
        int row = r0 + p;
        int w = t - row;
        const float4 z4 = make_float4(0.f, 0.f, 0.f, 0.f);
#pragma unroll
        for (int j = 0; j < 6; ++j) {
            int k = j * 64 + l * 4;
            float4 val;
            if (j < 2) {
                val = (w >= 0 && w < W)
                          ? *(const float4*)&xT[((size_t)(b * H + row) * W + w) * C + k]
                          : z4;
            } else if (j < 4) {
                val = (row > 0)
                          ? *(const float4*)&h_prev[(size_t)(b * H + row - 1) * C + (k - C)]
                          : z4;
            } else {
                val = *(const float4*)&h_prev[(size_t)(b * H + row) * C + (k - 2 * C)];
            }
            *(float4*)&v[p][k] = val;
        }
    }
    __syncthreads();

    int pp = tid >> 5, ch = tid & 31;
    int co = cg * 32 + ch;   // absolute channel 0..127
    int p0 = pp * 2;

    const float* wp0 = Wcat + (size_t)(0 * C + co) * KV;  // o-gate row
    const float* wp1 = Wcat + (size_t)(1 * C + co) * KV;  // f-gate row
    const float* wp2 = Wcat + (size_t)(2 * C + co) * KV;  // i-gate row
    const float* wp3 = Wcat + (size_t)(3 * C + co) * KV;  // g row

    float acc[4][2];
    acc[0][0] = acc[0][1] = biasW[0 * C + co];
    acc[1][0] = acc[1][1] = biasW[1 * C + co];
    acc[2][0] = acc[2][1] = biasW[2 * C + co];
    acc[3][0] = acc[3][1] = biasW[3 * C + co];

#pragma unroll 4
    for (int k = 0; k < KV / 4; ++k) {
        float4 vv0 = *(const float4*)&v[p0][k * 4];
        float4 vv1 = *(const float4*)&v[p0 + 1][k * 4];
        float4 q0 = *(const float4*)&wp0[k * 4];
        float4 q1 = *(const float4*)&wp1[k * 4];
        float4 q2 = *(const float4*)&wp2[k * 4];
        float4 q3 = *(const float4*)&wp3[k * 4];
        acc[0][0] += q0.x * vv0.x + q0.y * vv0.y + q0.z * vv0.z + q0.w * vv0.w;
        acc[0][1] += q0.x * vv1.x + q0.y * vv1.y + q0.z * vv1.z + q0.w * vv1.w;
        acc[1][0] += q1.x * vv0.x + q1.y * vv0.y + q1.z * vv0.z + q1.w * vv0.w;
        acc[1][1] += q1.x * vv1.x + q1.y * vv1.y + q1.z * vv1.z + q1.w * vv1.w;
        acc[2][0] += q2.x * vv0.x + q2.y * vv0.y + q2.z * vv0.z + q2.w * vv0.w;
        acc[2][1] += q2.x * vv1.x + q2.y * vv1.y + q2.z * vv1.z + q2.w * vv1.w;
        acc[3][0] += q3.x * vv0.x + q3.y * vv0.y + q3.z * vv0.z + q3.w * vv0.w;
        acc[3][1] += q3.x * vv1.x + q3.y * vv1.y + q3.z * vv1.z + q3.w * vv1.w;
    }

#pragma unroll
    for (int i = 0; i < 2; ++i) {
        int row = r0 + p0 + i;
        float og = 1.f / (1.f + __expf(-acc[0][i]));
        float fg = 1.f / (1.f + __expf(-acc[1][i]));
        float ig = 1.f / (1.f + __expf(-acc[2][i]));
        float gg = tanhf(acc[3][i]);
        size_t idx = (size_t)(b * H + row) * C + co;
        float cv = c_buf[idx];
        float cn = fg * cv + ig * gg;
        c_buf[idx] = cn;
        float hn = og * tanhf(cn);
        h_cur[idx] = hn;
        int w = t - row;
        if (w >= 0 && w < W)
            hist[((size_t)(b * H + row) * W + w) * C + co] = hn;
    }
}

// hist [B][H][W][C] -> out [B][C][H][W]
__global__ void unhist(const float* __restrict__ hist, float* __restrict__ out) {
    __shared__ float tile[W][C + 1];
    int b = blockIdx.x >> 6, row = blockIdx.x & 63;
    int tid = threadIdx.x;
#pragma unroll
    for (int i = 0; i < (C * W) / 256; ++i) {
        int idx = i * 256 + tid;
        int w = idx >> 7, c = idx & 127;
        tile[w][c] = hist[((size_t)(b * H + row) * W + w) * C + c];
    }
    __syncthreads();
#pragma unroll
    for (int i = 0; i < (C * W) / 256; ++i) {
        int idx = i * 256 + tid;
        int c = idx >> 6, w = idx & 63;
        out[((size_t)(b * C + c) * H + row) * W + w] = tile[w][c];
    }
}

} // namespace

extern "C" void kernel_launch(void* const* d_in, const int* in_sizes, int n_in,
                              void* d_out, int out_size, void* d_ws, size_t ws_size,
                              hipStream_t stream) {
    const float* x    = (const float*)d_in[0];
    const float* w_is = (const float*)d_in[1];
    const float* b_is = (const float*)d_in[2];
    const float* w_ss = (const float*)d_in[3];
    const float* b_ss = (const float*)d_in[4];
    float* out = (float*)d_out;

    float* wsf   = (float*)d_ws;
    float* Wcat  = wsf;                                   // 512*384
    float* biasW = Wcat + (size_t)NO * KV;                // 512
    float* xT    = biasW + 512;                           // B*H*W*C
    float* hist  = xT + (size_t)B * H * W * C;            // B*H*W*C
    float* h0    = hist + (size_t)B * H * W * C;          // B*H*C
    float* h1    = h0 + (size_t)B * H * C;                // B*H*C
    float* cb    = h1 + (size_t)B * H * C;                // B*H*C

    hipLaunchKernelGGL(pack_weights, dim3(NO), dim3(C), 0, stream,
                       w_is, b_is, w_ss, b_ss, Wcat, biasW);
    hipLaunchKernelGGL(transpose_x, dim3(B * H), dim3(256), 0, stream, x, xT);
    hipMemsetAsync(h0, 0, (size_t)B * H * C * sizeof(float), stream);
    hipMemsetAsync(cb, 0, (size_t)B * H * C * sizeof(float), stream);

    for (int t = 0; t < WSKEW; ++t) {
        const float* hp = (t & 1) ? h1 : h0;
        float* hc       = (t & 1) ? h0 : h1;
        hipLaunchKernelGGL(lstm_step, dim3(256), dim3(256), 0, stream,
                           xT, Wcat, biasW, hp, hc, cb, hist, t);
    }
    hipLaunchKernelGGL(unhist, dim3(B * H), dim3(256), 0, stream, hist, out);
}